// Round 9
// baseline (400.191 us; speedup 1.0000x reference)
//
#include <hip/hip_runtime.h>
#include <hip/hip_bf16.h>

typedef __attribute__((ext_vector_type(8))) short short8;
typedef __attribute__((ext_vector_type(4))) float f32x4;
typedef __attribute__((ext_vector_type(2))) unsigned int uint2v;

#define LOG2E 1.4426950408889634f
#define LN2   0.6931471805599453f

__device__ __forceinline__ unsigned short f2bf(float f) {
    union { float f; unsigned u; } v; v.f = f;
    unsigned u = v.u;
    u += 0x7fffu + ((u >> 16) & 1u);   // RNE, finite
    return (unsigned short)(u >> 16);
}
__device__ __forceinline__ float bf2f(unsigned short h) {
    union { unsigned u; float f; } v; v.u = ((unsigned)h) << 16;
    return v.f;
}
__device__ __forceinline__ unsigned pk_bf16(float a, float b) {
    __hip_bfloat162 t = __float22bfloat162_rn(float2{a, b});   // v_cvt_pk_bf16_f32
    union { __hip_bfloat162 b; unsigned u; } v; v.b = t;
    return v.u;
}

// ---------------------------------------------------------------------------
// Wave tile = 64 rows x 64 cols. Wave w owns phys cols [w*64, w*64+64).
// Tile->column map: col tile ct (0..3), frag col i: phys n = w*64 + 4*i + ct.
// Pack order per layer: frag-set ((w*NKS + ks)*4 + ct) -> contiguous 32 KB
// stream per wave per layer.
//   wp[(((w*NKS+ks)*4+ct)*64 + lane)*8 + j] = W[k][n],
//   k = ks*32 + (lane>>4)*8 + j,  n = w*64 + 4*(lane&15) + ct.
// W0: hi/lo split rows [wh,wl,wh] per input dim (K=9 pad 32, NKS=1); the
// matching A-side pattern is built in registers in the main kernel.
// negc[l*256+n] = -log2(e)/(2*sigma^2).
// ---------------------------------------------------------------------------
__global__ void pack_kernel(const float* __restrict__ W0, const float* __restrict__ W1,
                            const float* __restrict__ W2,
                            const float* __restrict__ s0, const float* __restrict__ s1,
                            const float* __restrict__ s2,
                            unsigned short* __restrict__ wp, float* __restrict__ negc) {
    int tid = blockIdx.x * 256 + threadIdx.x;    // 0 .. 139263
    if (tid < 8192) {                            // W0 (NKS=1)
        int j = tid & 7, lane = (tid >> 3) & 63, ct = (tid >> 9) & 3, w = tid >> 11;
        int k = ((lane >> 4) * 8) + j;           // 0..31
        int n = w * 64 + 4 * (lane & 15) + ct;
        unsigned short v = 0;
        if (k < 9) {
            int d = k / 3, m = k - d * 3;        // m: 0->wh 1->wl 2->wh
            float wv = W0[d * 256 + n];
            unsigned short wh = f2bf(wv);
            v = (m == 1) ? f2bf(wv - bf2f(wh)) : wh;
        }
        wp[tid] = v;
    } else if (tid < 139264) {                   // W1 / W2 (NKS=8)
        int e = tid - 8192;
        const float* W = W1;
        if (e >= 65536) { W = W2; e -= 65536; }
        int j = e & 7, lane = (e >> 3) & 63, ct = (e >> 9) & 3, ks = (e >> 11) & 7, w = e >> 14;
        int k = ks * 32 + ((lane >> 4) * 8) + j;
        int n = w * 64 + 4 * (lane & 15) + ct;
        wp[tid] = f2bf(W[k * 256 + n]);
    }
    if (tid < 768) {
        const float* s = (tid < 256) ? s0 : (tid < 512 ? s1 : s2);
        float sv = s[tid & 255];
        negc[tid] = -LOG2E / (2.0f * sv * sv);
    }
}

constexpr int ROWS = 64;     // rows per block (256 threads = 4 waves)
constexpr int HSTR = 264;    // h row stride, bf16 elems (+8 pad; 528 B)

// K-loop for LDS-sourced layers: wave covers all 64 rows x its 64 cols;
// per ks, 4 A-frags + 4 contiguous W-frags -> 16 MFMAs (each load feeds 4).
template <int NKS>
__device__ __forceinline__ void mfma_accum(const unsigned short* __restrict__ src,
                                           const unsigned short* __restrict__ wpk,
                                           int w, int i16, int q,
                                           f32x4 (&acc)[4][4]) {
#pragma unroll
    for (int rg = 0; rg < 4; ++rg)
#pragma unroll
        for (int ct = 0; ct < 4; ++ct)
            acc[rg][ct] = f32x4{0.f, 0.f, 0.f, 0.f};

    const int lane = q * 16 + i16;
    const short8* wp8 = (const short8*)wpk + (w * NKS * 4) * 64 + lane;
    const unsigned short* abase = src + i16 * HSTR + q * 8;

#pragma unroll
    for (int ks = 0; ks < NKS; ++ks) {
        short8 a[4];
#pragma unroll
        for (int rg = 0; rg < 4; ++rg)
            a[rg] = *(const short8*)(abase + rg * 16 * HSTR + ks * 32);
#pragma unroll
        for (int ct = 0; ct < 4; ++ct) {
            short8 wf = wp8[(ks * 4 + ct) * 64];
#pragma unroll
            for (int rg = 0; rg < 4; ++rg)
                acc[rg][ct] = __builtin_amdgcn_mfma_f32_16x16x32_bf16(a[rg], wf, acc[rg][ct], 0, 0, 0);
        }
    }
}

// Epilogue: bias + gauss -> b64 packed writes of bf16 activations.
__device__ __forceinline__ void store_act(f32x4 (&acc)[4][4],
                                          const float* __restrict__ bias,
                                          const float* __restrict__ ncp,
                                          unsigned short* __restrict__ hdst,
                                          int w, int i16, int q, bool presync) {
    const int ce = w * 64 + 4 * i16;
    const f32x4 bb = *(const f32x4*)(bias + ce);
    const f32x4 np = *(const f32x4*)(ncp + ce);
    uint2v av[4][4];
#pragma unroll
    for (int rg = 0; rg < 4; ++rg)
#pragma unroll
        for (int rr = 0; rr < 4; ++rr) {
            float x0 = acc[rg][0][rr] + bb[0];
            float x1 = acc[rg][1][rr] + bb[1];
            float x2 = acc[rg][2][rr] + bb[2];
            float x3 = acc[rg][3][rr] + bb[3];
            float g0 = __builtin_amdgcn_exp2f(x0 * x0 * np[0]);
            float g1 = __builtin_amdgcn_exp2f(x1 * x1 * np[1]);
            float g2 = __builtin_amdgcn_exp2f(x2 * x2 * np[2]);
            float g3 = __builtin_amdgcn_exp2f(x3 * x3 * np[3]);
            uint2v v;
            v[0] = pk_bf16(g0, g1);
            v[1] = pk_bf16(g2, g3);
            av[rg][rr] = v;
        }
    if (presync) __syncthreads();   // all reads of hdst done before overwrite
#pragma unroll
    for (int rg = 0; rg < 4; ++rg) {
        int rbase = rg * 16 + q * 4;
#pragma unroll
        for (int rr = 0; rr < 4; ++rr)
            *(uint2v*)&hdst[(rbase + rr) * HSTR + ce] = av[rg][rr];
    }
    __syncthreads();
}

__global__ __launch_bounds__(256, 4) void mlp_kernel(
    const float* __restrict__ pos,
    const float* __restrict__ b0, const float* __restrict__ b1,
    const float* __restrict__ b2,
    const float* __restrict__ W3, const float* __restrict__ b3,
    const unsigned short* __restrict__ Wp,
    const float* __restrict__ negc,
    float* __restrict__ out)
{
    __shared__ unsigned short h[ROWS * HSTR];   // 33792 B
    __shared__ float posS[ROWS * 3];            // 768 B  (34560 total -> 4 blk/CU)

    const int tid  = threadIdx.x;
    const int lane = tid & 63;
    const int wave = tid >> 6;                  // column group (0..3)
    const int i16  = lane & 15, q = lane >> 4;
    const long row0 = (long)blockIdx.x * ROWS;

    // ---- stage pos coalesced ----
    if (tid < ROWS * 3) posS[tid] = pos[row0 * 3 + tid];
    __syncthreads();

    {   // ---- layer 0: A-frags built IN REGISTERS (K=32 incl hi/lo split) ----
        // A row r K-vector: k=3d+{0,1,2} -> {ph,ph,pl} of dim d; k=8: p2l; k>8: 0.
        // Lane (i16,q) holds rows rg*16+i16, k = q*8..q*8+7.
        f32x4 acc[4][4];
#pragma unroll
        for (int rg = 0; rg < 4; ++rg)
#pragma unroll
            for (int ct = 0; ct < 4; ++ct)
                acc[rg][ct] = f32x4{0.f, 0.f, 0.f, 0.f};
        const short8* wp8 = (const short8*)Wp + (wave * 4) * 64 + lane;
        short8 wf[4];
#pragma unroll
        for (int ct = 0; ct < 4; ++ct) wf[ct] = wp8[ct * 64];
#pragma unroll
        for (int rg = 0; rg < 4; ++rg) {
            const float* pp = posS + (rg * 16 + i16) * 3;
            float p0 = pp[0], p1 = pp[1], p2 = pp[2];
            short h0 = (short)f2bf(p0); short l0 = (short)f2bf(p0 - bf2f((unsigned short)h0));
            short h1 = (short)f2bf(p1); short l1 = (short)f2bf(p1 - bf2f((unsigned short)h1));
            short h2 = (short)f2bf(p2); short l2 = (short)f2bf(p2 - bf2f((unsigned short)h2));
            short8 afull = short8{h0, h0, l0, h1, h1, l1, h2, h2};
            short8 atail = short8{l2, 0, 0, 0, 0, 0, 0, 0};
            short8 az    = short8{0, 0, 0, 0, 0, 0, 0, 0};
            short8 a = (q == 0) ? afull : ((q == 1) ? atail : az);
#pragma unroll
            for (int ct = 0; ct < 4; ++ct)
                acc[rg][ct] = __builtin_amdgcn_mfma_f32_16x16x32_bf16(a, wf[ct], acc[rg][ct], 0, 0, 0);
        }
        store_act(acc, b0, negc, h, wave, i16, q, false);
    }
    {   // ---- layer 1 ----
        f32x4 acc[4][4];
        mfma_accum<8>(h, Wp + 8192, wave, i16, q, acc);
        store_act(acc, b1, negc + 256, h, wave, i16, q, true);
    }
    {   // ---- layer 2 ----
        f32x4 acc[4][4];
        mfma_accum<8>(h, Wp + 73728, wave, i16, q, acc);
        store_act(acc, b2, negc + 512, h, wave, i16, q, true);
    }

    // ---- layer 4: dot(h_row, W3) + softplus(beta=1, thr=8) ----
    // 4 threads/row; thread qq sums col chunks (qq + 4i)*8 (bank-uniform).
    {
        int r = tid >> 2, qq = tid & 3;
        const unsigned short* hrow = h + r * HSTR;
        float s = 0.0f;
#pragma unroll
        for (int i = 0; i < 8; ++i) {
            int c = (qq + 4 * i) * 8;
            short8 hv = *(const short8*)(hrow + c);
            f32x4 wA = *(const f32x4*)(W3 + c);
            f32x4 wB = *(const f32x4*)(W3 + c + 4);
#pragma unroll
            for (int jj = 0; jj < 4; ++jj) {
                s = fmaf(bf2f((unsigned short)hv[jj]), wA[jj], s);
                s = fmaf(bf2f((unsigned short)hv[4 + jj]), wB[jj], s);
            }
        }
        s += __shfl_xor(s, 1);
        s += __shfl_xor(s, 2);
        if (qq == 0) {
            float x  = s + b3[0];
            float xm = fminf(x, 8.0f);
            float e  = __builtin_amdgcn_exp2f(xm * LOG2E);
            float sp = __builtin_amdgcn_logf(1.0f + e) * LN2;
            out[row0 + r] = (x > 8.0f) ? x : sp;
        }
    }
}

extern "C" void kernel_launch(void* const* d_in, const int* in_sizes, int n_in,
                              void* d_out, int out_size, void* d_ws, size_t ws_size,
                              hipStream_t stream) {
    const float* pos = (const float*)d_in[0];
    const float* W0  = (const float*)d_in[1];
    const float* b0  = (const float*)d_in[2];
    const float* W1  = (const float*)d_in[3];
    const float* b1  = (const float*)d_in[4];
    const float* W2  = (const float*)d_in[5];
    const float* b2  = (const float*)d_in[6];
    const float* W3  = (const float*)d_in[7];
    const float* b3  = (const float*)d_in[8];
    const float* s0  = (const float*)d_in[9];
    const float* s1  = (const float*)d_in[10];
    const float* s2  = (const float*)d_in[11];

    unsigned short* wp = (unsigned short*)d_ws;              // 139264 bf16
    float* negc = (float*)((char*)d_ws + 278528);            // 768 fp32

    pack_kernel<<<544, 256, 0, stream>>>(W0, W1, W2, s0, s1, s2, wp, negc);

    int nrows = in_sizes[0] / 3;          // 1048576
    int nblk  = nrows / ROWS;             // 16384
    mlp_kernel<<<nblk, 256, 0, stream>>>(pos, b0, b1, b2, W3, b3, wp, negc,
                                         (float*)d_out);
}